// Round 2
// baseline (307.752 us; speedup 1.0000x reference)
//
#include <hip/hip_runtime.h>
#include <math.h>

#define IMG_H 512
#define IMG_W 512
#define NCELL 64     // cells per dim (512/8)
#define NORI 9

// ---------------------------------------------------------------------------
// Bit-exact transcription of glibc/FDLIBM float atan / atan2 (flt-32 Sun code)
// — what numpy's np.arctan2 float32 loop resolves to on glibc <= 2.40.
// v3: INLINED (no call — calls forced caller-save spills / regalloc limits in
// round 0), with the runtime-indexed atanhi/atanlo tables converted to
// 4-way selects so nothing lands in scratch (rule: runtime-indexed arrays
// go to local memory). Reached only for ~2e-4 of pixels, branch-guarded.
// ---------------------------------------------------------------------------
__device__ __forceinline__ float fdlibm_atanf_inl(float x) {
#pragma clang fp contract(off)
    const float one = 1.0f;
    int hx = __float_as_int(x);
    int ix = hx & 0x7fffffff;
    int id;
    if (ix >= 0x4c800000) {                 // |x| >= 2^26
        const float v = 1.5707962513e+00f + 7.5497894159e-08f;  // folded in f32
        return (hx > 0) ? v : -v;
    }
    if (ix < 0x3ee00000) {                  // |x| < 0.4375
        if (ix < 0x39800000) return x;      // |x| < 2^-12
        id = -1;
    } else {
        x = fabsf(x);
        if (ix < 0x3f980000) {              // |x| < 1.1875
            if (ix < 0x3f300000) { id = 0; x = (2.0f * x - one) / (2.0f + x); }
            else                 { id = 1; x = (x - one) / (x + one); }
        } else {
            if (ix < 0x401c0000) { id = 2; x = (x - 1.5f) / (one + 1.5f * x); }
            else                 { id = 3; x = -1.0f / x; }
        }
    }
    float z = x * x;
    float w = z * z;
    float s1 = z * (3.3333334327e-01f + w * (1.4285714924e-01f + w * (9.0908870101e-02f
             + w * (6.6610731184e-02f + w * (4.9768779427e-02f + w * 1.6285819933e-02f)))));
    float s2 = w * (-2.0000000298e-01f + w * (-1.1111110449e-01f + w * (-7.6918758452e-02f
             + w * (-5.8335702866e-02f + w * -3.6531571299e-02f))));
    if (id < 0) return x - x * (s1 + s2);
    const float hi = (id == 0) ? 4.6364760399e-01f : (id == 1) ? 7.8539812565e-01f
                   : (id == 2) ? 9.8279368877e-01f : 1.5707962513e+00f;
    const float lo = (id == 0) ? 5.0121582440e-09f : (id == 1) ? 3.7748947079e-08f
                   : (id == 2) ? 3.4473217170e-08f : 7.5497894159e-08f;
    z = hi - ((x * (s1 + s2) - lo) - x);
    return (hx < 0) ? -z : z;
}

__device__ __forceinline__ int fdlibm_bin_inl(float y, float x) {
#pragma clang fp contract(off)
    // exact reference chain: fdlibm atan2f -> f32 rad2deg -> numpy mod -> bin
    const float tiny   = 1.0e-30f;
    const float pi_o_2 = 1.5707963705e+00f;   // 0x3FC90FDB
    const float pi     = 3.1415927410e+00f;   // 0x40490FDB
    const float pi_lo  = -8.7422776573e-08f;  // 0xB3BBBD2E

    int hx = __float_as_int(x), ix = hx & 0x7fffffff;
    int hy = __float_as_int(y), iy = hy & 0x7fffffff;
    float th;
    if (hx == 0x3f800000) { th = fdlibm_atanf_inl(y); }    // x == 1.0
    else {
        int m = ((hy >> 31) & 1) | ((hx >> 30) & 2);       // 2*sign(x)+sign(y)
        if (iy == 0) {                                      // y == +-0
            switch (m) {
                case 0:
                case 1: th = y; break;
                case 2: th =  pi + tiny; break;
                default: th = -pi - tiny; break;
            }
        } else if (ix == 0) {
            th = (hy < 0) ? -pi_o_2 - tiny : pi_o_2 + tiny; // x == +-0
        } else {
            int k = (iy - ix) >> 23;
            float z;
            int mm = m;
            if (k > 26) {                                   // |y/x| > 2^26
                z = pi_o_2 + 0.5f * pi_lo;
                mm &= 1;
            } else if (k < -26 && hx < 0) {
                z = 0.0f;
            } else {
                z = fdlibm_atanf_inl(fabsf(y / x));
            }
            switch (mm) {
                case 0:  th = z; break;
                case 1:  th = -z; break;
                case 2:  th = pi - (z - pi_lo); break;
                default: th = (z - pi_lo) - pi; break;
            }
        }
    }
    const float RAD2DEG = (float)(180.0 / 3.14159265358979311600e+00);
    float m = fmodf(th * RAD2DEG, 180.0f);                  // numpy remainder semantics
    if (m < 0.0f) m += 180.0f;                              // (can round up to exactly 180)
    int o = (int)(m * 0.05f);
    if (o < 9) {                                            // exact boundary fix-up
        if (m < 20.0f * (float)o) --o;
        else if (m >= 20.0f * (float)(o + 1)) ++o;
    }
    return o;                                               // may be 9 (== exactly 180): no bin
}

// ---------------------------------------------------------------------------
// Fused HOG kernel. One block per (batch, strip of 8 block-rows); 512 threads.
// Grid 512 = exactly 2 blocks/CU (16 waves/CU), all resident, zero tail.
// Per step r (hist row): prefetch gray group r+2 into regs -> compute hist
// row r (LDS ping-pong) -> barrier -> ds_write prefetched group + normalize
// block-row r-1 straight to the output -> barrier. 3-slot circular gray
// buffer; NO global hist, NO workspace, NO atomics, NO calls.
// ---------------------------------------------------------------------------
__global__ __launch_bounds__(512, 4) void hog_fused_kernel(const float* __restrict__ x,
                                                           float* __restrict__ out) {
#pragma clang fp contract(off)
    const int bid = blockIdx.x;
    const int b   = bid >> 3;          // batch
    const int s   = bid & 7;           // strip
    const int r0  = s * 8;             // first hist row of strip
    const int SL  = (s == 7) ? 7 : 8;  // hist rows r0..r0+SL; block-rows r0..r0+SL-1
    const int t   = threadIdx.x;

    __shared__ __align__(16) float gbuf[3][8][IMG_W];     // 48 KB circular gray groups
    __shared__ __align__(16) float histL[2][NCELL * NORI]; // 4.6 KB hist ping-pong

    const float GW0 = 0.2125f, GW1 = 0.7154f, GW2 = 0.0721f;
    const float PIF   = 3.14159265358979323846f;
    const float PIO2F = 1.57079632679489662f;
    const float PIO4F = 0.78539816339744831f;

    // ---- prologue: stage gray groups r0-1, r0, r0+1 (mirror-clamped rows) ----
    {
        float4 A[6], C[6], D[6];
#pragma unroll
        for (int k = 0; k < 6; ++k) {
            const int gi = k >> 1;                 // 0..2 -> group r0-1+gi
            const int pq = t + 512 * (k & 1);      // 0..1023 pixel-quad in group
            const int rr = pq >> 7, grp = pq & 127;
            int h = (r0 - 1 + gi) * 8 + rr;
            if (h < 0)   h = 1;                    // mirror: gr == +0.0 at row 0
            if (h > 511) h = 510;                  // mirror: gr == +0.0 at row 511
            const float4* p4 = (const float4*)x + (size_t)(b * IMG_H + h) * (IMG_W * 3 / 4)
                               + (size_t)grp * 3;
            A[k] = p4[0]; C[k] = p4[1]; D[k] = p4[2];   // all 18 loads in flight
        }
#pragma unroll
        for (int k = 0; k < 6; ++k) {
            const int gi = k >> 1;
            const int sl = (r0 - 1 + gi + 3) % 3;  // slot(g) = (g+3)%3
            const int pq = t + 512 * (k & 1);
            const int rr = pq >> 7, wg = (pq & 127) * 4;
            float4 gv;
            gv.x = __builtin_fmaf(A[k].z, GW2, __builtin_fmaf(A[k].y, GW1, A[k].x * GW0));
            gv.y = __builtin_fmaf(C[k].y, GW2, __builtin_fmaf(C[k].x, GW1, A[k].w * GW0));
            gv.z = __builtin_fmaf(D[k].x, GW2, __builtin_fmaf(C[k].w, GW1, C[k].z * GW0));
            gv.w = __builtin_fmaf(D[k].w, GW2, __builtin_fmaf(D[k].z, GW1, D[k].y * GW0));
            *(float4*)&gbuf[sl][rr][wg] = gv;
        }
    }
    __syncthreads();

    const int w   = t;                               // pixel column 0..511
    const int wl  = (w == 0)   ? 0   : w - 1;
    const int wr  = (w == 511) ? 511 : w + 1;
    const bool wok = (w >= 1) && (w <= 510);
    const int c   = w >> 3;                          // cell column
    const int jl  = t & 7;                           // lane within cell

    for (int r = r0; r <= r0 + SL; ++r) {
        // ---- (1) prefetch next gray group (r+2) into registers ----
        const bool pf = (r < r0 + SL);
        float4 A[2], C[2], D[2];
        if (pf) {
#pragma unroll
            for (int k = 0; k < 2; ++k) {
                const int pq = t + 512 * k;
                const int rr = pq >> 7, grp = pq & 127;
                int h = (r + 2) * 8 + rr;            // >= 16: no low clamp
                if (h > 511) h = 510;
                const float4* p4 = (const float4*)x + (size_t)(b * IMG_H + h) * (IMG_W * 3 / 4)
                                   + (size_t)grp * 3;
                A[k] = p4[0]; C[k] = p4[1]; D[k] = p4[2];
            }
        }

        // ---- (2) compute hist row r from gray rows 8r-1..8r+8 ----
        const int slA = (r + 2) % 3;   // slot(r-1): row 7 = halo top
        const int slB = r % 3;         // slot(r):  rows 0..7
        const int slC = (r + 1) % 3;   // slot(r+1): row 0 = halo bottom
        float cc[10], ee[8], ww[8];
        cc[0] = gbuf[slA][7][w];
        cc[9] = gbuf[slC][0][w];
#pragma unroll
        for (int i = 0; i < 8; ++i) {
            cc[i + 1] = gbuf[slB][i][w];
            ee[i]     = gbuf[slB][i][wr];
            ww[i]     = gbuf[slB][i][wl];
        }

        float bh[9];
#pragma unroll
        for (int k = 0; k < 9; ++k) bh[k] = 0.0f;

#pragma unroll
        for (int j = 0; j < 8; ++j) {
            const float gr = cc[j + 2] - cc[j];          // +0.0 at image edge rows
            const float gc = wok ? (ee[j] - ww[j]) : 0.0f;
            const float mag = __builtin_amdgcn_sqrtf(__builtin_fmaf(gr, gr, gc * gc));

            // fast octant-reduced atan: red <=> mn/mx > tan(pi/8), one rcp
            const float ax = fabsf(gc), ay = fabsf(gr);
            const float mx = fmaxf(ax, ay), mn = fminf(ax, ay);
            const bool red = mn > 0.4142135624f * mx;
            const float num = red ? (mn - mx) : mn;
            const float den = red ? (mn + mx) : mx;
            const float xx  = num * __builtin_amdgcn_rcpf(den);  // 1-ulp rcp: err << guard
            const float z   = xx * xx;
            // Cephes atanf minimax, |x|<=0.4142: rel err ~2.4e-8
            float y = __builtin_fmaf(
                        __builtin_fmaf(
                          __builtin_fmaf(8.05374449538e-2f, z, -1.38776856032e-1f),
                          z, 1.99777106478e-1f),
                        z, -3.33329491539e-1f);
            float r0a = __builtin_fmaf(y * z, xx, xx);   // atan(xx)
            if (red)        r0a = PIO4F + r0a;
            if (ay > ax)    r0a = PIO2F - r0a;
            if (gc < 0.0f)  r0a = PIF - r0a;
            if (gr < 0.0f)  r0a = PIF - r0a;             // theta mod pi
            const float q    = (r0a * 57.295779513082323f) * 0.05f;
            int o            = (int)q;                   // (int)NaN==0 on gfx950: safe
            const float frac = q - (float)o;
            bool suspect = (frac < 1e-4f) || (frac > 0.9999f) || (o > 8);
            if (ay == 0.0f) { o = 0; suspect = false; }  // exact: ref chain gives bin 0
            if (__builtin_expect(suspect, 0)) {
                o = fdlibm_bin_inl(gr, gc);              // inlined, no call; o may be 9
            }
#pragma unroll
            for (int k = 0; k < 9; ++k) bh[k] += (o == k) ? mag : 0.0f;  // o==9: no bin
        }

        // 8-lane butterfly per cell; lane jl stores bin jl (lane 0 also bin 8)
#pragma unroll
        for (int k = 0; k < 9; ++k) {
            bh[k] += __shfl_xor(bh[k], 1, 64);
            bh[k] += __shfl_xor(bh[k], 2, 64);
            bh[k] += __shfl_xor(bh[k], 4, 64);
        }
        float mv = bh[0];
#pragma unroll
        for (int k = 1; k < 8; ++k) mv = (jl == k) ? bh[k] : mv;
        histL[r & 1][c * NORI + jl] = mv * 0.015625f;    // /64 cell area
        if (jl == 0) histL[r & 1][c * NORI + 8] = bh[8] * 0.015625f;

        __syncthreads();   // B1: histL row r visible; gray reads of slA complete

        // ---- (3) ds_write prefetched group r+2 into slot(r+2)==slA ----
        if (pf) {
#pragma unroll
            for (int k = 0; k < 2; ++k) {
                const int pq = t + 512 * k;
                const int rr = pq >> 7, wg = (pq & 127) * 4;
                float4 gv;
                gv.x = __builtin_fmaf(A[k].z, GW2, __builtin_fmaf(A[k].y, GW1, A[k].x * GW0));
                gv.y = __builtin_fmaf(C[k].y, GW2, __builtin_fmaf(C[k].x, GW1, A[k].w * GW0));
                gv.z = __builtin_fmaf(D[k].x, GW2, __builtin_fmaf(C[k].w, GW1, C[k].z * GW0));
                gv.w = __builtin_fmaf(D[k].w, GW2, __builtin_fmaf(D[k].z, GW1, D[k].y * GW0));
                *(float4*)&gbuf[slA][rr][wg] = gv;
            }
        }

        // ---- (4) normalize block-row r-1 (needs hist rows r-1, r) ----
        if (r > r0 && t < 252) {
            const int cb = t >> 2;     // block column 0..62
            const int l  = t & 3;      // (i,j) within 2x2
            const int bi = l >> 1, bj = l & 1;
            const int br = r - 1;
            const float* v = &histL[(br + bi) & 1][(cb + bj) * NORI];
            float vv[9];
            float ss = 0.0f;
#pragma unroll
            for (int k = 0; k < 9; ++k) { vv[k] = v[k]; ss += vv[k] * vv[k]; }
            ss += __shfl_xor(ss, 1, 64);
            ss += __shfl_xor(ss, 2, 64);
            const float rn1 = 1.0f / sqrtf(ss + 1e-10f);       // EPS^2 = 1e-10
            float ss2 = 0.0f;
#pragma unroll
            for (int k = 0; k < 9; ++k) { vv[k] = fminf(vv[k] * rn1, 0.2f); ss2 += vv[k] * vv[k]; }
            ss2 += __shfl_xor(ss2, 1, 64);
            ss2 += __shfl_xor(ss2, 2, 64);
            const float rn2 = 1.0f / sqrtf(ss2 + 1e-10f);
            float* od = out + (size_t)(b * 63 + br) * (63 * 36) + (cb * 36 + l * 9);
#pragma unroll
            for (int k = 0; k < 9; ++k) od[k] = vv[k] * rn2;
        }

        __syncthreads();   // B2: histL[(r-1)&1] free to overwrite; gray slot slA valid
    }
}

extern "C" void kernel_launch(void* const* d_in, const int* in_sizes, int n_in,
                              void* d_out, int out_size, void* d_ws, size_t ws_size,
                              hipStream_t stream) {
    const float* x = (const float*)d_in[0];
    float* out     = (float*)d_out;
    (void)d_ws; (void)ws_size;   // workspace intentionally UNUSED (ws-poison test)

    hog_fused_kernel<<<dim3(64 * 8), dim3(512), 0, stream>>>(x, out);
}

// Round 3
// 296.761 us; speedup vs baseline: 1.0370x; 1.0370x over previous
//
#include <hip/hip_runtime.h>
#include <math.h>

#define IMG_H 512
#define IMG_W 512
#define NCELL 64     // cells per dim (512/8)
#define NORI 9

// ---------------------------------------------------------------------------
// Bit-exact transcription of glibc/FDLIBM float atan / atan2 (flt-32 Sun code)
// — what numpy's np.arctan2 float32 loop resolves to on glibc <= 2.40.
// INLINED (no-call version verified passing in round 2): runtime-indexed
// tables converted to selects so nothing spills to scratch. Reached only for
// ~5e-4 of pixels (near-bin-boundary suspects), branch-guarded.
// ---------------------------------------------------------------------------
__device__ __forceinline__ float fdlibm_atanf_inl(float x) {
#pragma clang fp contract(off)
    const float one = 1.0f;
    int hx = __float_as_int(x);
    int ix = hx & 0x7fffffff;
    int id;
    if (ix >= 0x4c800000) {                 // |x| >= 2^26
        const float v = 1.5707962513e+00f + 7.5497894159e-08f;  // folded in f32
        return (hx > 0) ? v : -v;
    }
    if (ix < 0x3ee00000) {                  // |x| < 0.4375
        if (ix < 0x39800000) return x;      // |x| < 2^-12
        id = -1;
    } else {
        x = fabsf(x);
        if (ix < 0x3f980000) {              // |x| < 1.1875
            if (ix < 0x3f300000) { id = 0; x = (2.0f * x - one) / (2.0f + x); }
            else                 { id = 1; x = (x - one) / (x + one); }
        } else {
            if (ix < 0x401c0000) { id = 2; x = (x - 1.5f) / (one + 1.5f * x); }
            else                 { id = 3; x = -1.0f / x; }
        }
    }
    float z = x * x;
    float w = z * z;
    float s1 = z * (3.3333334327e-01f + w * (1.4285714924e-01f + w * (9.0908870101e-02f
             + w * (6.6610731184e-02f + w * (4.9768779427e-02f + w * 1.6285819933e-02f)))));
    float s2 = w * (-2.0000000298e-01f + w * (-1.1111110449e-01f + w * (-7.6918758452e-02f
             + w * (-5.8335702866e-02f + w * -3.6531571299e-02f))));
    if (id < 0) return x - x * (s1 + s2);
    const float hi = (id == 0) ? 4.6364760399e-01f : (id == 1) ? 7.8539812565e-01f
                   : (id == 2) ? 9.8279368877e-01f : 1.5707962513e+00f;
    const float lo = (id == 0) ? 5.0121582440e-09f : (id == 1) ? 3.7748947079e-08f
                   : (id == 2) ? 3.4473217170e-08f : 7.5497894159e-08f;
    z = hi - ((x * (s1 + s2) - lo) - x);
    return (hx < 0) ? -z : z;
}

__device__ __forceinline__ int fdlibm_bin_inl(float y, float x) {
#pragma clang fp contract(off)
    // exact reference chain: fdlibm atan2f -> f32 rad2deg -> numpy mod -> bin
    const float tiny   = 1.0e-30f;
    const float pi_o_2 = 1.5707963705e+00f;   // 0x3FC90FDB
    const float pi     = 3.1415927410e+00f;   // 0x40490FDB
    const float pi_lo  = -8.7422776573e-08f;  // 0xB3BBBD2E

    int hx = __float_as_int(x), ix = hx & 0x7fffffff;
    int hy = __float_as_int(y), iy = hy & 0x7fffffff;
    float th;
    if (hx == 0x3f800000) { th = fdlibm_atanf_inl(y); }    // x == 1.0
    else {
        int m = ((hy >> 31) & 1) | ((hx >> 30) & 2);       // 2*sign(x)+sign(y)
        if (iy == 0) {                                      // y == +-0
            switch (m) {
                case 0:
                case 1: th = y; break;
                case 2: th =  pi + tiny; break;
                default: th = -pi - tiny; break;
            }
        } else if (ix == 0) {
            th = (hy < 0) ? -pi_o_2 - tiny : pi_o_2 + tiny; // x == +-0
        } else {
            int k = (iy - ix) >> 23;
            float z;
            int mm = m;
            if (k > 26) {                                   // |y/x| > 2^26
                z = pi_o_2 + 0.5f * pi_lo;
                mm &= 1;
            } else if (k < -26 && hx < 0) {
                z = 0.0f;
            } else {
                z = fdlibm_atanf_inl(fabsf(y / x));
            }
            switch (mm) {
                case 0:  th = z; break;
                case 1:  th = -z; break;
                case 2:  th = pi - (z - pi_lo); break;
                default: th = (z - pi_lo) - pi; break;
            }
        }
    }
    const float RAD2DEG = (float)(180.0 / 3.14159265358979311600e+00);
    float m = fmodf(th * RAD2DEG, 180.0f);                  // numpy remainder semantics
    if (m < 0.0f) m += 180.0f;                              // (can round up to exactly 180)
    int o = (int)(m * 0.05f);
    if (o < 9) {                                            // exact boundary fix-up
        if (m < 20.0f * (float)o) --o;
        else if (m >= 20.0f * (float)(o + 1)) ++o;
    }
    return o;                                               // may be 9 (== exactly 180): no bin
}

// ---------------------------------------------------------------------------
// Kernel 1 v3: per-cell orientation histograms.
// 512 threads (one column each, 8 waves/block), launch_bounds(512,6) ->
// 24 waves/CU. Binning via 8 INDEPENDENT sector cross-products
//   o = #{ k : gy*cos(20k) - gx*sin(20k) >= 0 },  (gy,gx)=(|gr|, gr<0?-gc:gc)
// (dep depth ~3 vs ~60 for the atan chain; no transcendental but sqrt).
// Suspects (any |c_k| < 1e-4*mag, or near-180 f32-rounding zone) take the
// inlined exact fdlibm chain. gy==0 is analytically bin 0 (proven r0/r1).
// No atomics, no calls; register 9-bin hist + 8-lane butterfly + coalesced
// store to the workspace (ws poison proven unconditional -> workspace free).
// ---------------------------------------------------------------------------
__global__ __launch_bounds__(512, 6) void hog_hist_kernel(const float* __restrict__ x,
                                                          float* __restrict__ hist) {
#pragma clang fp contract(off)
    const int bid = blockIdx.x;
    const int b   = bid >> 6;     // batch
    const int cr  = bid & 63;     // cell row
    const int t   = threadIdx.x;
    const int h0  = cr * 8;

    __shared__ __align__(16) float g[10][IMG_W];       // 20 KB gray strip + halo rows

    // ---- stage gray rows; halo rows MIRRORED so edge gr == +0.0 exactly ----
    const float GW0 = 0.2125f, GW1 = 0.7154f, GW2 = 0.0721f;
    float4 A[3], C[3], D[3];
#pragma unroll
    for (int k = 0; k < 3; ++k) {
        const int gi = t + 512 * k;           // 0..1535; need 0..1279
        if (k < 2 || t < 256) {
            const int rr = gi >> 7;           // 0..9
            int h = h0 - 1 + rr;
            if (h < 0)   h = 1;               // g[0]:=gray(row1)=g[2] -> gr=0 at h=0
            if (h > 511) h = 510;             // g[9]:=gray(row510)=g[7] -> gr=0 at h=511
            const int grp = gi & 127;         // 4-pixel group within row
            const float4* p4 = (const float4*)x + (size_t)(b * IMG_H + h) * (IMG_W * 3 / 4)
                               + (size_t)grp * 3;
            A[k] = p4[0]; C[k] = p4[1]; D[k] = p4[2];   // all loads in flight
        }
    }
#pragma unroll
    for (int k = 0; k < 3; ++k) {
        const int gi = t + 512 * k;
        if (k < 2 || t < 256) {
            const int rr = gi >> 7;
            const int wg = (gi & 127) * 4;
            float4 gv;
            gv.x = __builtin_fmaf(A[k].z, GW2, __builtin_fmaf(A[k].y, GW1, A[k].x * GW0));
            gv.y = __builtin_fmaf(C[k].y, GW2, __builtin_fmaf(C[k].x, GW1, A[k].w * GW0));
            gv.z = __builtin_fmaf(D[k].x, GW2, __builtin_fmaf(C[k].w, GW1, C[k].z * GW0));
            gv.w = __builtin_fmaf(D[k].w, GW2, __builtin_fmaf(D[k].z, GW1, D[k].y * GW0));
            *(float4*)&g[rr][wg] = gv;
        }
    }
    __syncthreads();

    // ---- per-pixel gradient, magnitude, orientation bin (one column/thread) ----
    const int w   = t;                              // pixel column 0..511
    const int wl  = (w == 0)   ? 0   : w - 1;
    const int wr  = (w == 511) ? 511 : w + 1;
    const bool wok = (w >= 1) && (w <= 510);
    const int c   = w >> 3;                         // cell column
    const int jl  = t & 7;                          // lane within cell

    // batch-preload: all independent ds_reads issued up front
    float cc[10], ee[8], ww[8];
#pragma unroll
    for (int i = 0; i < 10; ++i) cc[i] = g[i][w];
#pragma unroll
    for (int i = 0; i < 8; ++i) { ee[i] = g[i + 1][wr]; ww[i] = g[i + 1][wl]; }

    // sector boundary constants (20k degrees), f32-rounded
    const float CK[8] = { 0.9396926208f,  0.7660444431f,  0.5f,            0.1736481777f,
                         -0.1736481777f, -0.5f,           -0.7660444431f, -0.9396926208f };
    const float SK[8] = { 0.3420201433f,  0.6427876097f,  0.8660254038f,  0.9848077530f,
                          0.9848077530f,  0.8660254038f,  0.6427876097f,  0.3420201433f };

    float bh[9];
#pragma unroll
    for (int k = 0; k < 9; ++k) bh[k] = 0.0f;

#pragma unroll
    for (int r = 0; r < 8; ++r) {
        const float gr = cc[r + 2] - cc[r];              // +0.0 at image edge rows
        const float gc = wok ? (ee[r] - ww[r]) : 0.0f;
        const float mag = __builtin_amdgcn_sqrtf(__builtin_fmaf(gr, gr, gc * gc));

        const float gy = fabsf(gr);
        const float gx = (gr < 0.0f) ? -gc : gc;         // theta mod 180 representative
        const float th = 1e-4f * mag;                    // suspect margin (~0.006 deg)
        int  o = 0;
        bool suspect = false;
#pragma unroll
        for (int k = 0; k < 8; ++k) {
            const float ck = __builtin_fmaf(gy, CK[k], -(gx * SK[k]));
            o += (ck >= 0.0f) ? 1 : 0;
            suspect = suspect || (fabsf(ck) < th);
        }
        // f32 near-180 zone: atan2f can round to pi exactly -> ref deg>=180 ->
        // mod wraps to bin 0 / no-bin. Sector test can't see this; defer.
        suspect = suspect || ((gx < 0.0f) && (gy < 1e-5f * fabsf(gc)));
        if (gy == 0.0f) { o = 0; suspect = false; }      // exact: ref chain -> bin 0
        if (__builtin_expect(suspect, 0)) {
            o = fdlibm_bin_inl(gr, gc);                  // inlined exact; may be 9
        }
#pragma unroll
        for (int k = 0; k < 9; ++k) bh[k] += (o == k) ? mag : 0.0f;  // o==9: no bin
    }

    // reduce the 8 lanes of each cell (lanes are contiguous groups of 8)
#pragma unroll
    for (int k = 0; k < 9; ++k) {
        bh[k] += __shfl_xor(bh[k], 1, 64);
        bh[k] += __shfl_xor(bh[k], 2, 64);
        bh[k] += __shfl_xor(bh[k], 4, 64);
    }
    // lane jl of the cell stores bin jl (contiguous across the wave), lane 0 bin 8
    float mv = bh[0];
#pragma unroll
    for (int k = 1; k < 8; ++k) mv = (jl == k) ? bh[k] : mv;
    float* hout = hist + (size_t)(b * NCELL + cr) * (NCELL * NORI);
    hout[c * NORI + jl] = mv * 0.015625f;                // /64 cell area
    if (jl == 0) hout[c * NORI + 8] = bh[8] * 0.015625f;
}

// ---------------------------------------------------------------------------
// Kernel 2: 2x2 block gathering + double L2-hys normalization.
// (round-1 verified version) zero LDS, zero barriers. 4 lanes per output
// block (one cell each): 9 dword loads (hist L2-hot), quad shfl_xor
// butterflies for the norms, 9 dword stores per lane (block-contiguous).
// ---------------------------------------------------------------------------
__global__ __launch_bounds__(256) void hog_norm_kernel(const float* __restrict__ hist,
                                                       float* __restrict__ out) {
#pragma clang fp contract(off)
    const int bid = blockIdx.x;
    const int b   = bid / 63;
    const int r   = bid % 63;
    const int t   = threadIdx.x;
    const int c   = t >> 2;      // block column 0..63 (63 used)
    const int l   = t & 3;       // (i,j) within 2x2
    if (c >= 63) return;

    const int bi = l >> 1, bj = l & 1;
    const float* v = hist + ((size_t)(b * NCELL + r + bi) * NCELL + (c + bj)) * NORI;

    float vv[9];
    float ss = 0.0f;
#pragma unroll
    for (int k = 0; k < 9; ++k) { vv[k] = v[k]; ss += vv[k] * vv[k]; }
    ss += __shfl_xor(ss, 1, 64);
    ss += __shfl_xor(ss, 2, 64);
    const float rn1 = 1.0f / sqrtf(ss + 1e-10f);            // EPS^2 = 1e-10
    float ss2 = 0.0f;
#pragma unroll
    for (int k = 0; k < 9; ++k) { vv[k] = fminf(vv[k] * rn1, 0.2f); ss2 += vv[k] * vv[k]; }
    ss2 += __shfl_xor(ss2, 1, 64);
    ss2 += __shfl_xor(ss2, 2, 64);
    const float rn2 = 1.0f / sqrtf(ss2 + 1e-10f);

    float* od = out + (size_t)bid * (63 * 36) + (c * 36 + l * 9);
#pragma unroll
    for (int k = 0; k < 9; ++k) od[k] = vv[k] * rn2;
}

extern "C" void kernel_launch(void* const* d_in, const int* in_sizes, int n_in,
                              void* d_out, int out_size, void* d_ws, size_t ws_size,
                              hipStream_t stream) {
    const float* x = (const float*)d_in[0];
    float* out     = (float*)d_out;
    float* hist    = (float*)d_ws;   // 64*64*64*9 floats = 9.4 MB scratch

    hog_hist_kernel<<<dim3(64 * 64), dim3(512), 0, stream>>>(x, hist);
    hog_norm_kernel<<<dim3(64 * 63), dim3(256), 0, stream>>>(hist, out);
}